// Round 13
// baseline (700.881 us; speedup 1.0000x reference)
//
#include <hip/hip_runtime.h>

// ---------------------------------------------------------------------------
// MORAL 2-layer GCN on MI355X — round 13.
//   A/B within one run:
//   - Layer 1 aggregate: XCD-PINNED sliced gather. g1/h1 stored slice-major
//     [8][N][16 cols]; each block reads HW_REG_XCC_ID and serves ITS XCD's
//     slice via a per-XCD dst-chunk queue (ctrl[16..23]) + steal fallback
//     (correct under any dispatch). Gather pool per XCD = 3.2MB (L2-fit).
//   - Layer 2 aggregate: r11's row-major kernel, unchanged = 68us control.
//   gemm1: fp32 in -> sliced out (r12-verified epilogue).
//   gemm2: sliced bf16 in (r12-verified A-path) -> row-major out (r11).
//   Everything else identical to r11 (best total: 278.6us).
// ---------------------------------------------------------------------------

typedef short bf16x8 __attribute__((ext_vector_type(8)));
typedef float f32x4 __attribute__((ext_vector_type(4)));
typedef unsigned short ushort_t;

__device__ __forceinline__ unsigned encf(float f) {
  unsigned u = __float_as_uint(f);
  return (u & 0x80000000u) ? ~u : (u | 0x80000000u);
}
__device__ __forceinline__ float decf(unsigned e) {
  unsigned u = (e & 0x80000000u) ? (e ^ 0x80000000u) : ~e;
  return __uint_as_float(u);
}
__device__ __forceinline__ ushort_t f2bf(float f) {
  unsigned u = __float_as_uint(f);
  u += 0x7FFF + ((u >> 16) & 1);  // RNE
  return (ushort_t)(u >> 16);
}
__device__ __forceinline__ float bf2f(ushort_t h) {
  return __uint_as_float((unsigned)h << 16);
}
__device__ __forceinline__ float bflo(unsigned v) {
  return __uint_as_float(v << 16);
}
__device__ __forceinline__ float bfhi(unsigned v) {
  return __uint_as_float(v & 0xFFFF0000u);
}

// ---- init + edge-dtype detect ----------------------------------------------
__global__ void init_kernel(const int* __restrict__ edges, int E, int* flag64,
                            unsigned* minenc, unsigned* maxenc, int* ovf_deg,
                            int* bcur, int* ctrl, int N) {
  int i = blockIdx.x * blockDim.x + threadIdx.x;
  if (i < 128) { minenc[i] = 0xFFFFFFFFu; maxenc[i] = 0u; }
  if (i < 2048) bcur[i] = 0;
  if (i < 32) ctrl[i] = 0;
  if (i < N) ovf_deg[i] = 0;
  if (blockIdx.x == 0) {
    __shared__ int any_nz;
    if (threadIdx.x == 0) any_nz = 0;
    __syncthreads();
    int idx = 2 * (int)threadIdx.x + 1;
    if (threadIdx.x < 128 && idx < 2 * E && edges[idx] != 0) any_nz = 1;
    __syncthreads();
    if (threadIdx.x == 0) *flag64 = !any_nz;
  }
}

__global__ void colminmax_kernel(const float* __restrict__ x, unsigned* minenc,
                                 unsigned* maxenc, int N) {
  int g = blockIdx.x * blockDim.x + threadIdx.x;
  int col = g & 127;
  int r0 = g >> 7;
  int nstream = (gridDim.x * blockDim.x) >> 7;
  float mn = 3.4e38f, mx = -3.4e38f;
  for (int r = r0; r < N; r += nstream) {
    float v = x[(size_t)r * 128 + col];
    mn = fminf(mn, v); mx = fmaxf(mx, v);
  }
  atomicMin(&minenc[col], encf(mn));
  atomicMax(&maxenc[col], encf(mx));
}

// Wt1[j][k] = bf16(s[k]*W1[k][j]); cvec[j] = sum_k mn[k]*float(Wt1[j][k])
__global__ __launch_bounds__(1024) void prep_kernel(
    const unsigned* __restrict__ minenc, const unsigned* __restrict__ maxenc,
    const float* __restrict__ W1, const float* __restrict__ W2,
    ushort_t* __restrict__ Wt1, ushort_t* __restrict__ Wt2,
    float* __restrict__ cvec, float* __restrict__ czero) {
  __shared__ float mn_s[128], s_s[128];
  __shared__ float csum[8][128];
  int tid = threadIdx.x;
  int j = tid & 127, kg = tid >> 7;
  if (tid < 128) {
    float mn = decf(minenc[tid]);
    float mx = decf(maxenc[tid]);
    mn_s[tid] = mn;
    s_s[tid] = 1.0f / ((mx > mn) ? (mx - mn) : 1.0f);
  }
  __syncthreads();
  ushort_t w1buf[16], w2buf[16];
  float c = 0.f;
#pragma unroll
  for (int kk = 0; kk < 16; ++kk) {
    int k = kg * 16 + kk;
    float wp = s_s[k] * W1[k * 128 + j];
    ushort_t wb = f2bf(wp);
    w1buf[kk] = wb;
    c += mn_s[k] * bf2f(wb);
    w2buf[kk] = f2bf(W2[k * 128 + j]);
  }
  {
    uint4* p1 = (uint4*)(Wt1 + j * 128 + kg * 16);
    uint4* p2 = (uint4*)(Wt2 + j * 128 + kg * 16);
    p1[0] = *(uint4*)&w1buf[0]; p1[1] = *(uint4*)&w1buf[8];
    p2[0] = *(uint4*)&w2buf[0]; p2[1] = *(uint4*)&w2buf[8];
  }
  csum[kg][j] = c;
  __syncthreads();
  if (tid < 128) {
    float t = 0.f;
#pragma unroll
    for (int x = 0; x < 8; ++x) t += csum[x][tid];
    cvec[tid] = t;
    czero[tid] = 0.f;
  }
}

// ---- Phase 1: MSB-radix partition (r11) -------------------------------------
#define PITER 8
#define PCHUNK 2048

__global__ __launch_bounds__(256) void partition_kernel(
    const void* __restrict__ edges, int E, const int* __restrict__ flag64,
    unsigned* __restrict__ staging, int capx,
    int* __restrict__ ovf, int ovfcap, int* __restrict__ ovf_deg,
    int* __restrict__ bcur, int* __restrict__ ctrl,
    int srcbits, unsigned M, int width) {
  __shared__ unsigned pk_s[PCHUNK];
  __shared__ unsigned char bk_s[PCHUNK];
  __shared__ int hist[256], rbase[256], lcur[256];
  __shared__ int chunk_s;
  int xcd;
  asm volatile("s_getreg_b32 %0, hwreg(HW_REG_XCC_ID)" : "=s"(xcd));
  xcd &= 7;
  const int elo = (int)(((long long)E * xcd) >> 3);
  const int ehi = (int)(((long long)E * (xcd + 1)) >> 3);
  const int is64 = *flag64;
  const int tid = threadIdx.x;

  for (;;) {
    __syncthreads();
    if (tid == 0) chunk_s = atomicAdd(&ctrl[xcd], 1);
    hist[tid] = 0;
    __syncthreads();
    int base = elo + chunk_s * PCHUNK;
    if (base >= ehi) break;
    int cnt = ehi - base; if (cnt > PCHUNK) cnt = PCHUNK;
#pragma unroll
    for (int i = 0; i < PITER; ++i) {
      int idx = i * 256 + tid;
      if (idx < cnt) {
        int e = base + idx;
        int s, d;
        if (is64) {
          s = (int)__builtin_nontemporal_load((const long long*)edges + e);
          d = (int)__builtin_nontemporal_load((const long long*)edges + E + e);
        } else {
          s = __builtin_nontemporal_load((const int*)edges + e);
          d = __builtin_nontemporal_load((const int*)edges + E + e);
        }
        unsigned b = __umulhi((unsigned)d, M);
        int dloc = d - (int)b * width;
        pk_s[idx] = ((unsigned)dloc << srcbits) | (unsigned)s;
        bk_s[idx] = (unsigned char)b;
        atomicAdd(&hist[b], 1);
      }
    }
    __syncthreads();
    {
      int h = hist[tid];
      rbase[tid] = h ? atomicAdd(&bcur[xcd * 256 + tid], h) : 0;
      lcur[tid] = 0;
    }
    __syncthreads();
#pragma unroll
    for (int i = 0; i < PITER; ++i) {
      int idx = i * 256 + tid;
      if (idx < cnt) {
        int b = bk_s[idx];
        unsigned p = pk_s[idx];
        int j = atomicAdd(&lcur[b], 1);
        int pos = rbase[b] + j;
        if (pos < capx) {
          staging[((size_t)(xcd * 256 + b)) * capx + pos] = p;
        } else {
          int op = atomicAdd(&ctrl[8], 1);
          if (op < ovfcap) {
            int s = (int)(p & ((1u << srcbits) - 1u));
            int d = b * width + (int)(p >> srcbits);
            ovf[2 * op] = s; ovf[2 * op + 1] = d;
            atomicAdd(&ovf_deg[d], 1);
          }
        }
      }
    }
  }
}

// ---- Phase 2: per-bucket build (r11) -----------------------------------------
#define WMAX 512
#define BLDS 12288

__global__ __launch_bounds__(256) void build_kernel(
    const unsigned* __restrict__ staging, int capx,
    const int* __restrict__ bcur, const int* __restrict__ ovf_deg,
    const int* __restrict__ ovf, int ovfcap, const int* __restrict__ ctrl,
    int* __restrict__ rowptr, int* __restrict__ gcursor,
    float* __restrict__ dinv, int* __restrict__ adj,
    int N, int E, int srcbits, int width) {
  __shared__ int cntS[WMAX], scn[WMAX], lcur[WMAX];
  __shared__ unsigned items[BLDS];
  __shared__ int sbase;
  int b = blockIdx.x;
  int tid = threadIdx.x;
  int nlo = b * width;
  int wcnt = N - nlo; if (wcnt > width) wcnt = width; if (wcnt < 0) wcnt = 0;

  for (int i = tid; i < WMAX; i += 256) cntS[i] = 0;

  int t0 = 0;
#pragma unroll
  for (int x = 0; x < 8; ++x) t0 += bcur[x * 256 + tid];
  scn[tid] = t0;
  __syncthreads();
  for (int off = 1; off < 256; off <<= 1) {
    int v = (tid >= off) ? scn[tid - off] : 0;
    __syncthreads();
    scn[tid] += v;
    __syncthreads();
  }
  if (tid == b) sbase = scn[b] - t0;
  __syncthreads();
  int base = sbase;

  int lens[8], offx[8], tot = 0;
#pragma unroll
  for (int x = 0; x < 8; ++x) {
    int l = bcur[x * 256 + b]; if (l > capx) l = capx;
    lens[x] = l; offx[x] = tot; tot += l;
  }
  bool fits = (tot <= BLDS);

  for (int x = 0; x < 8; ++x) {
    const unsigned* sp = staging + ((size_t)(x * 256 + b)) * capx;
    int len = lens[x], ox = offx[x];
    for (int i = tid; i < len; i += 256) {
      unsigned p = sp[i];
      if (fits) items[ox + i] = p;
      atomicAdd(&cntS[p >> srcbits], 1);
    }
  }
  __syncthreads();

  for (int i = tid; i < WMAX; i += 256)
    scn[i] = cntS[i] + ((i < wcnt) ? ovf_deg[nlo + i] : 0);
  __syncthreads();
  for (int off = 1; off < WMAX; off <<= 1) {
    int i0 = tid, i1 = tid + 256;
    int v0 = (i0 >= off) ? scn[i0 - off] : 0;
    int v1 = (i1 >= off) ? scn[i1 - off] : 0;
    __syncthreads();
    scn[i0] += v0; scn[i1] += v1;
    __syncthreads();
  }

  for (int i = tid; i < WMAX; i += 256) {
    int ov = (i < wcnt) ? ovf_deg[nlo + i] : 0;
    int orig = cntS[i] + ov;
    int ex = scn[i] - orig;
    lcur[i] = ex;
    if (i < wcnt) {
      rowptr[nlo + i] = base + ex;
      gcursor[nlo + i] = base + ex + cntS[i];
      dinv[nlo + i] = rsqrtf((float)orig + 1.0f);
    }
  }
  if (b == gridDim.x - 1 && tid == 0) rowptr[N] = E;
  __syncthreads();

  if (fits) {
    for (int i = tid; i < tot; i += 256) {
      unsigned p = items[i];
      int pos = atomicAdd(&lcur[p >> srcbits], 1);
      adj[base + pos] = (int)(p & ((1u << srcbits) - 1u));
    }
  } else {
    for (int x = 0; x < 8; ++x) {
      const unsigned* sp = staging + ((size_t)(x * 256 + b)) * capx;
      int len = lens[x];
      for (int i = tid; i < len; i += 256) {
        unsigned p = sp[i];
        int pos = atomicAdd(&lcur[p >> srcbits], 1);
        adj[base + pos] = (int)(p & ((1u << srcbits) - 1u));
      }
    }
  }
  __syncthreads();

  int ovlen = ctrl[8]; if (ovlen > ovfcap) ovlen = ovfcap;
  if (ovlen > 0) {
    int nhi = nlo + wcnt;
    for (int i = tid; i < ovlen; i += 256) {
      int s = ovf[2 * i], d = ovf[2 * i + 1];
      if (d >= nlo && d < nhi) {
        int pos = atomicAdd(&gcursor[d], 1);
        adj[pos] = s;
      }
    }
  }
}

// ---- MFMA GEMM --------------------------------------------------------------
// XMODE: 0 = fp32 row-major X; 1 = bf16 sliced X ([8][N][16]).
// OUTSLICED: 1 = write sliced bf16 g; 0 = write row-major bf16 g.
template <int XMODE, int OUTSLICED>
__global__ __launch_bounds__(256) void gemm_mfma_kernel(
    const void* __restrict__ Xv, const ushort_t* __restrict__ Wtg,
    const float* __restrict__ cvec, const float* __restrict__ dinv,
    ushort_t* __restrict__ g, int N) {
  __shared__ ushort_t wt[128 * 128];  // XOR-swizzled
  int t = threadIdx.x;
  for (int c = t; c < 2048; c += 256) {
    int j = c >> 4;
    int ko = (c & 15) << 4;
    uint4 v = *(const uint4*)(Wtg + j * 128 + (ko >> 1));
    *(uint4*)((char*)wt + j * 256 + (ko ^ ((j & 7) << 4))) = v;
  }
  __syncthreads();

  int lane = t & 63, w = t >> 6;
  int lrow = lane & 15;
  int lk = lane >> 4;
  int rowA = blockIdx.x * 64 + w * 16 + lrow;
  int rA = (rowA < N) ? rowA : (N - 1);

  f32x4 acc[8];
#pragma unroll
  for (int i = 0; i < 8; ++i) acc[i] = (f32x4){0.f, 0.f, 0.f, 0.f};

#pragma unroll
  for (int ks = 0; ks < 4; ++ks) {
    int k0 = ks * 32;
    bf16x8 a;
    if (XMODE == 1) {
      int k = k0 + lk * 8;
      const ushort_t* hp =
          (const ushort_t*)Xv + ((size_t)(k >> 4) * N + rA) * 16 + (k & 15);
      a = *(const bf16x8*)hp;
    } else {
      const float* xp = (const float*)Xv + (size_t)rA * 128 + k0 + lk * 8;
      float4 f0 = *(const float4*)xp;
      float4 f1 = *(const float4*)(xp + 4);
      bf16x8 tmp;
      tmp[0] = (short)f2bf(f0.x); tmp[1] = (short)f2bf(f0.y);
      tmp[2] = (short)f2bf(f0.z); tmp[3] = (short)f2bf(f0.w);
      tmp[4] = (short)f2bf(f1.x); tmp[5] = (short)f2bf(f1.y);
      tmp[6] = (short)f2bf(f1.z); tmp[7] = (short)f2bf(f1.w);
      a = tmp;
    }
    int koff = k0 * 2 + lk * 16;
#pragma unroll
    for (int tl = 0; tl < 8; ++tl) {
      int j = tl * 16 + lrow;
      bf16x8 bfr = *(const bf16x8*)((const char*)wt + j * 256 + (koff ^ ((j & 7) << 4)));
      acc[tl] = __builtin_amdgcn_mfma_f32_16x16x32_bf16(a, bfr, acc[tl], 0, 0, 0);
    }
  }

  int robase = blockIdx.x * 64 + w * 16 + (lane >> 4) * 4;
#pragma unroll
  for (int j = 0; j < 4; ++j) {
    int row = robase + j;
    if (row < N) {
      float dv = dinv[row];
#pragma unroll
      for (int tl = 0; tl < 8; ++tl) {
        float o = (acc[tl][j] - cvec[tl * 16 + lrow]) * dv;
        if (OUTSLICED)
          g[((size_t)tl * N + row) * 16 + lrow] = f2bf(o);
        else
          g[(size_t)row * 128 + tl * 16 + lrow] = f2bf(o);
      }
    }
  }
}

// ---- aggregate A: XCD-pinned sliced gather (layer 1) ------------------------
// g sliced [8][N][16]; block's slice = its REAL XCD id; per-XCD dst-chunk
// queue in ctrl[16..23] with stealing (correct under any dispatch).
// h1 out sliced bf16 with relu.
__global__ __launch_bounds__(256) void aggregate_sliced_kernel(
    const int* __restrict__ rowptr, const int* __restrict__ adj,
    const ushort_t* __restrict__ g, const float* __restrict__ dinv,
    const float* __restrict__ b, ushort_t* __restrict__ out,
    int* __restrict__ ctrl, int N) {
  __shared__ int chunk_s;
  int xcd;
  asm volatile("s_getreg_b32 %0, hwreg(HW_REG_XCC_ID)" : "=s"(xcd));
  xcd &= 7;
  int tid = threadIdx.x;
  int dg = tid >> 3;   // dst-group 0..31 within chunk
  int l8 = tid & 7;    // 2 cols per lane

  for (int qi = 0; qi < 8; ++qi) {
    int q = (xcd + qi) & 7;  // own slice first, then steal
    const ushort_t* gs = g + (size_t)q * N * 16 + l8 * 2;
    for (;;) {
      __syncthreads();
      if (tid == 0) chunk_s = atomicAdd(&ctrl[16 + q], 1);
      __syncthreads();
      int base = chunk_s * 32;
      if (base >= N) break;
      int d = base + dg;
      if (d < N) {
        unsigned sv = *(const unsigned*)(gs + (size_t)d * 16);  // self loop
        float a0 = bflo(sv), a1 = bfhi(sv);

        int beg = rowptr[d], end = rowptr[d + 1];
        int i = beg;
        for (; i + 3 < end; i += 4) {
          int n0 = __builtin_nontemporal_load(adj + i);
          int n1 = __builtin_nontemporal_load(adj + i + 1);
          int n2 = __builtin_nontemporal_load(adj + i + 2);
          int n3 = __builtin_nontemporal_load(adj + i + 3);
          unsigned v0 = *(const unsigned*)(gs + (size_t)n0 * 16);
          unsigned v1 = *(const unsigned*)(gs + (size_t)n1 * 16);
          unsigned v2 = *(const unsigned*)(gs + (size_t)n2 * 16);
          unsigned v3 = *(const unsigned*)(gs + (size_t)n3 * 16);
          a0 += (bflo(v0) + bflo(v1)) + (bflo(v2) + bflo(v3));
          a1 += (bfhi(v0) + bfhi(v1)) + (bfhi(v2) + bfhi(v3));
        }
        for (; i < end; ++i) {
          int n = __builtin_nontemporal_load(adj + i);
          unsigned v = *(const unsigned*)(gs + (size_t)n * 16);
          a0 += bflo(v); a1 += bfhi(v);
        }

        float dv = dinv[d];
        const float2 bb = *(const float2*)&b[q * 16 + l8 * 2];
        float o0 = fmaxf(dv * a0 + bb.x, 0.f);
        float o1 = fmaxf(dv * a1 + bb.y, 0.f);
        unsigned ov = (unsigned)f2bf(o0) | ((unsigned)f2bf(o1) << 16);
        *(unsigned*)(out + ((size_t)q * N + d) * 16 + l8 * 2) = ov;
      }
    }
  }
}

// ---- aggregate B: row-major (r11 control, layer 2) --------------------------
__global__ __launch_bounds__(256) void aggregate_rm_kernel(
    const int* __restrict__ rowptr, const int* __restrict__ adj,
    const ushort_t* __restrict__ g, const float* __restrict__ dinv,
    const float* __restrict__ b, float* __restrict__ out, int N) {
  int t = blockIdx.x * blockDim.x + threadIdx.x;
  int d = t >> 6;
  if (d >= N) return;
  int lane = t & 63;
  int sub = lane >> 4;
  int l = lane & 15;
  const ushort_t* gp = g + l * 8;

  float a0 = 0.f, a1 = 0.f, a2 = 0.f, a3 = 0.f,
        a4 = 0.f, a5 = 0.f, a6 = 0.f, a7 = 0.f;
  if (sub == 0) {
    bf16x8 sv = *(const bf16x8*)(gp + (size_t)d * 128);
    a0 = bf2f(sv[0]); a1 = bf2f(sv[1]); a2 = bf2f(sv[2]); a3 = bf2f(sv[3]);
    a4 = bf2f(sv[4]); a5 = bf2f(sv[5]); a6 = bf2f(sv[6]); a7 = bf2f(sv[7]);
  }

  int beg = rowptr[d], end = rowptr[d + 1];
  int i = beg + sub;
  for (; i + 12 < end; i += 16) {
    int n0 = adj[i], n1 = adj[i + 4], n2 = adj[i + 8], n3 = adj[i + 12];
    bf16x8 v0 = *(const bf16x8*)(gp + (size_t)n0 * 128);
    bf16x8 v1 = *(const bf16x8*)(gp + (size_t)n1 * 128);
    bf16x8 v2 = *(const bf16x8*)(gp + (size_t)n2 * 128);
    bf16x8 v3 = *(const bf16x8*)(gp + (size_t)n3 * 128);
    a0 += (bf2f(v0[0]) + bf2f(v1[0])) + (bf2f(v2[0]) + bf2f(v3[0]));
    a1 += (bf2f(v0[1]) + bf2f(v1[1])) + (bf2f(v2[1]) + bf2f(v3[1]));
    a2 += (bf2f(v0[2]) + bf2f(v1[2])) + (bf2f(v2[2]) + bf2f(v3[2]));
    a3 += (bf2f(v0[3]) + bf2f(v1[3])) + (bf2f(v2[3]) + bf2f(v3[3]));
    a4 += (bf2f(v0[4]) + bf2f(v1[4])) + (bf2f(v2[4]) + bf2f(v3[4]));
    a5 += (bf2f(v0[5]) + bf2f(v1[5])) + (bf2f(v2[5]) + bf2f(v3[5]));
    a6 += (bf2f(v0[6]) + bf2f(v1[6])) + (bf2f(v2[6]) + bf2f(v3[6]));
    a7 += (bf2f(v0[7]) + bf2f(v1[7])) + (bf2f(v2[7]) + bf2f(v3[7]));
  }
  for (; i + 4 < end; i += 8) {
    int n0 = adj[i], n1 = adj[i + 4];
    bf16x8 v0 = *(const bf16x8*)(gp + (size_t)n0 * 128);
    bf16x8 v1 = *(const bf16x8*)(gp + (size_t)n1 * 128);
    a0 += bf2f(v0[0]) + bf2f(v1[0]); a1 += bf2f(v0[1]) + bf2f(v1[1]);
    a2 += bf2f(v0[2]) + bf2f(v1[2]); a3 += bf2f(v0[3]) + bf2f(v1[3]);
    a4 += bf2f(v0[4]) + bf2f(v1[4]); a5 += bf2f(v0[5]) + bf2f(v1[5]);
    a6 += bf2f(v0[6]) + bf2f(v1[6]); a7 += bf2f(v0[7]) + bf2f(v1[7]);
  }
  for (; i < end; i += 4) {
    int n = adj[i];
    bf16x8 v = *(const bf16x8*)(gp + (size_t)n * 128);
    a0 += bf2f(v[0]); a1 += bf2f(v[1]); a2 += bf2f(v[2]); a3 += bf2f(v[3]);
    a4 += bf2f(v[4]); a5 += bf2f(v[5]); a6 += bf2f(v[6]); a7 += bf2f(v[7]);
  }

  a0 += __shfl_xor(a0, 16); a1 += __shfl_xor(a1, 16);
  a2 += __shfl_xor(a2, 16); a3 += __shfl_xor(a3, 16);
  a4 += __shfl_xor(a4, 16); a5 += __shfl_xor(a5, 16);
  a6 += __shfl_xor(a6, 16); a7 += __shfl_xor(a7, 16);
  a0 += __shfl_xor(a0, 32); a1 += __shfl_xor(a1, 32);
  a2 += __shfl_xor(a2, 32); a3 += __shfl_xor(a3, 32);
  a4 += __shfl_xor(a4, 32); a5 += __shfl_xor(a5, 32);
  a6 += __shfl_xor(a6, 32); a7 += __shfl_xor(a7, 32);

  if (sub == 0) {
    float dv = dinv[d];
    const float4 bb0 = *(const float4*)&b[l * 8];
    const float4 bb1 = *(const float4*)&b[l * 8 + 4];
    float4 w0, w1;
    w0.x = dv * a0 + bb0.x; w0.y = dv * a1 + bb0.y;
    w0.z = dv * a2 + bb0.z; w0.w = dv * a3 + bb0.w;
    w1.x = dv * a4 + bb1.x; w1.y = dv * a5 + bb1.y;
    w1.z = dv * a6 + bb1.z; w1.w = dv * a7 + bb1.w;
    float* op = out + (size_t)d * 128 + l * 8;
    *(float4*)op = w0;
    *(float4*)(op + 4) = w1;
  }
}

extern "C" void kernel_launch(void* const* d_in, const int* in_sizes, int n_in,
                              void* d_out, int out_size, void* d_ws, size_t ws_size,
                              hipStream_t stream) {
  const float* features = (const float*)d_in[0];
  const float* W1 = (const float*)d_in[1];
  const float* b1 = (const float*)d_in[2];
  const float* W2 = (const float*)d_in[3];
  const float* b2 = (const float*)d_in[4];
  const void* edges = d_in[5];
  const int N = in_sizes[0] / 128;
  const int E = in_sizes[5] / 2;

  int srcbits = 1; while ((1LL << srcbits) < (long long)N) srcbits++;
  const int width = (N + 255) / 256;
  const unsigned M = (unsigned)(0x100000000ULL / (unsigned)width + 1);
  const int capx = (E / 2048) * 3 + 256;
  const int ovfcap = E / 4;

  float* ws = (float*)d_ws;
  size_t off = 0;
  ushort_t* gbuf = (ushort_t*)(ws + off);  off += (size_t)N * 64;  // g1 sliced / g2 row-major
  ushort_t* h1 = (ushort_t*)(ws + off);    off += (size_t)N * 64;  // h1 sliced bf16
  int* rowptr = (int*)(ws + off);      off += N + 4;
  int* gcursor = (int*)(ws + off);     off += N + 4;
  int* adj = (int*)(ws + off);         off += E;
  int* ovf_deg = (int*)(ws + off);     off += N + 4;
  float* dinv = ws + off;              off += N + 4;
  unsigned* minenc = (unsigned*)(ws + off); off += 128;
  unsigned* maxenc = (unsigned*)(ws + off); off += 128;
  ushort_t* Wt1 = (ushort_t*)(ws + off);    off += 128 * 64;
  ushort_t* Wt2 = (ushort_t*)(ws + off);    off += 128 * 64;
  float* cvec = ws + off;              off += 128;
  float* czero = ws + off;             off += 128;
  int* flag64 = (int*)(ws + off);      off += 4;
  int* ctrl = (int*)(ws + off);        off += 32;
  int* bcur = (int*)(ws + off);        off += 2048;
  unsigned* staging = (unsigned*)(ws + off); off += (size_t)2048 * capx;
  int* ovf = (int*)(ws + off);         off += 2 * (size_t)ovfcap;

  float* outf = (float*)d_out;

  // ---- graph + weight prep ----
  init_kernel<<<(N + 255) / 256, 256, 0, stream>>>(
      (const int*)edges, E, flag64, minenc, maxenc, ovf_deg, bcur, ctrl, N);
  colminmax_kernel<<<512, 256, 0, stream>>>(features, minenc, maxenc, N);
  prep_kernel<<<1, 1024, 0, stream>>>(minenc, maxenc, W1, W2, Wt1, Wt2, cvec, czero);
  partition_kernel<<<1024, 256, 0, stream>>>(edges, E, flag64, staging, capx,
                                             ovf, ovfcap, ovf_deg, bcur, ctrl,
                                             srcbits, M, width);
  build_kernel<<<256, 256, 0, stream>>>(staging, capx, bcur, ovf_deg,
                                        ovf, ovfcap, ctrl,
                                        rowptr, gcursor, dinv, adj,
                                        N, E, srcbits, width);

  // ---- layer 1: sliced pipeline (A-side of the A/B) ----
  gemm_mfma_kernel<0, 1><<<(N + 63) / 64, 256, 0, stream>>>(
      features, Wt1, cvec, dinv, gbuf, N);
  aggregate_sliced_kernel<<<2048, 256, 0, stream>>>(
      rowptr, adj, gbuf, dinv, b1, h1, ctrl, N);

  // ---- layer 2: row-major pipeline (B-side control) ----
  gemm_mfma_kernel<1, 0><<<(N + 63) / 64, 256, 0, stream>>>(
      h1, Wt2, czero, dinv, gbuf, N);
  aggregate_rm_kernel<<<((size_t)N * 64 + 255) / 256, 256, 0, stream>>>(
      rowptr, adj, gbuf, dinv, b2, outf, N);
}

// Round 14
// 322.969 us; speedup vs baseline: 2.1701x; 2.1701x over previous
//
#include <hip/hip_runtime.h>

// ---------------------------------------------------------------------------
// MORAL 2-layer GCN on MI355X — round 14.
//   = r11 (best, 278.6us) with two independent-work fusions:
//   - colminmax folded into partition launch (blocks [0,512) = colminmax,
//     [512,1536) = partition). Partition now steals across XCD edge-slice
//     queues, so correctness never assumes dispatch balance.
//   - prep folded into build as block #256 (256-thread variant).
//   Aggregates (68us, at gather-request floor per r8/r9/r10/r12/r13 evidence)
//   and GEMMs byte-identical to r11. 9 launches -> 7.
// ---------------------------------------------------------------------------

typedef short bf16x8 __attribute__((ext_vector_type(8)));
typedef float f32x4 __attribute__((ext_vector_type(4)));
typedef unsigned short ushort_t;

__device__ __forceinline__ unsigned encf(float f) {
  unsigned u = __float_as_uint(f);
  return (u & 0x80000000u) ? ~u : (u | 0x80000000u);
}
__device__ __forceinline__ float decf(unsigned e) {
  unsigned u = (e & 0x80000000u) ? (e ^ 0x80000000u) : ~e;
  return __uint_as_float(u);
}
__device__ __forceinline__ ushort_t f2bf(float f) {
  unsigned u = __float_as_uint(f);
  u += 0x7FFF + ((u >> 16) & 1);  // RNE
  return (ushort_t)(u >> 16);
}
__device__ __forceinline__ float bf2f(ushort_t h) {
  return __uint_as_float((unsigned)h << 16);
}

// ---- init + edge-dtype detect ----------------------------------------------
__global__ void init_kernel(const int* __restrict__ edges, int E, int* flag64,
                            unsigned* minenc, unsigned* maxenc, int* ovf_deg,
                            int* bcur, int* ctrl, int N) {
  int i = blockIdx.x * blockDim.x + threadIdx.x;
  if (i < 128) { minenc[i] = 0xFFFFFFFFu; maxenc[i] = 0u; }
  if (i < 2048) bcur[i] = 0;
  if (i < 32) ctrl[i] = 0;
  if (i < N) ovf_deg[i] = 0;
  if (blockIdx.x == 0) {
    __shared__ int any_nz;
    if (threadIdx.x == 0) any_nz = 0;
    __syncthreads();
    int idx = 2 * (int)threadIdx.x + 1;
    if (threadIdx.x < 128 && idx < 2 * E && edges[idx] != 0) any_nz = 1;
    __syncthreads();
    if (threadIdx.x == 0) *flag64 = !any_nz;
  }
}

// ---- fused: colminmax (blocks [0,CMB)) + MSB-radix partition (rest) ---------
#define PITER 8
#define PCHUNK 2048
#define CMB 512

__global__ __launch_bounds__(256) void partition_kernel(
    const float* __restrict__ x,
    unsigned* __restrict__ minenc, unsigned* __restrict__ maxenc,
    const void* __restrict__ edges, int E, const int* __restrict__ flag64,
    unsigned* __restrict__ staging, int capx,
    int* __restrict__ ovf, int ovfcap, int* __restrict__ ovf_deg,
    int* __restrict__ bcur, int* __restrict__ ctrl,
    int srcbits, unsigned M, int width, int N) {
  __shared__ unsigned pk_s[PCHUNK];
  __shared__ unsigned char bk_s[PCHUNK];
  __shared__ int hist[256], rbase[256], lcur[256];
  __shared__ int chunk_s;
  const int tid = threadIdx.x;

  if (blockIdx.x < CMB) {  // ---- colminmax role ----
    int g = blockIdx.x * 256 + tid;
    int col = g & 127;
    int r0 = g >> 7;
    const int nstream = (CMB * 256) >> 7;
    float mn = 3.4e38f, mx = -3.4e38f;
    for (int r = r0; r < N; r += nstream) {
      float v = x[(size_t)r * 128 + col];
      mn = fminf(mn, v); mx = fmaxf(mx, v);
    }
    atomicMin(&minenc[col], encf(mn));
    atomicMax(&maxenc[col], encf(mx));
    return;
  }

  // ---- partition role (with cross-slice steal; correct under any dispatch) --
  int xcd;
  asm volatile("s_getreg_b32 %0, hwreg(HW_REG_XCC_ID)" : "=s"(xcd));
  xcd &= 7;
  const int is64 = *flag64;

  for (int qi = 0; qi < 8; ++qi) {
    int q = (xcd + qi) & 7;  // own edge slice first, then steal
    const int elo = (int)(((long long)E * q) >> 3);
    const int ehi = (int)(((long long)E * (q + 1)) >> 3);
    for (;;) {
      __syncthreads();
      if (tid == 0) chunk_s = atomicAdd(&ctrl[q], 1);
      hist[tid] = 0;
      __syncthreads();
      int base = elo + chunk_s * PCHUNK;
      if (base >= ehi) break;
      int cnt = ehi - base; if (cnt > PCHUNK) cnt = PCHUNK;
#pragma unroll
      for (int i = 0; i < PITER; ++i) {
        int idx = i * 256 + tid;
        if (idx < cnt) {
          int e = base + idx;
          int s, d;
          if (is64) {
            s = (int)__builtin_nontemporal_load((const long long*)edges + e);
            d = (int)__builtin_nontemporal_load((const long long*)edges + E + e);
          } else {
            s = __builtin_nontemporal_load((const int*)edges + e);
            d = __builtin_nontemporal_load((const int*)edges + E + e);
          }
          unsigned b = __umulhi((unsigned)d, M);
          int dloc = d - (int)b * width;
          pk_s[idx] = ((unsigned)dloc << srcbits) | (unsigned)s;
          bk_s[idx] = (unsigned char)b;
          atomicAdd(&hist[b], 1);
        }
      }
      __syncthreads();
      {
        int h = hist[tid];
        rbase[tid] = h ? atomicAdd(&bcur[xcd * 256 + tid], h) : 0;
        lcur[tid] = 0;
      }
      __syncthreads();
#pragma unroll
      for (int i = 0; i < PITER; ++i) {
        int idx = i * 256 + tid;
        if (idx < cnt) {
          int b = bk_s[idx];
          unsigned p = pk_s[idx];
          int j = atomicAdd(&lcur[b], 1);
          int pos = rbase[b] + j;
          if (pos < capx) {
            staging[((size_t)(xcd * 256 + b)) * capx + pos] = p;
          } else {
            int op = atomicAdd(&ctrl[8], 1);
            if (op < ovfcap) {
              int s = (int)(p & ((1u << srcbits) - 1u));
              int d = b * width + (int)(p >> srcbits);
              ovf[2 * op] = s; ovf[2 * op + 1] = d;
              atomicAdd(&ovf_deg[d], 1);
            }
          }
        }
      }
    }
  }
}

// ---- fused: per-bucket build (blocks 0..255) + prep (block 256) -------------
#define WMAX 512
#define BLDS 12288

__global__ __launch_bounds__(256) void build_kernel(
    const unsigned* __restrict__ staging, int capx,
    const int* __restrict__ bcur, const int* __restrict__ ovf_deg,
    const int* __restrict__ ovf, int ovfcap, const int* __restrict__ ctrl,
    int* __restrict__ rowptr, int* __restrict__ gcursor,
    float* __restrict__ dinv, int* __restrict__ adj,
    const unsigned* __restrict__ minenc, const unsigned* __restrict__ maxenc,
    const float* __restrict__ W1, const float* __restrict__ W2,
    ushort_t* __restrict__ Wt1, ushort_t* __restrict__ Wt2,
    float* __restrict__ cvec, float* __restrict__ czero,
    int N, int E, int srcbits, int width) {
  __shared__ int cntS[WMAX], scn[WMAX], lcur[WMAX];
  __shared__ unsigned items[BLDS];
  __shared__ int sbase;
  __shared__ float mn_s[128], s_s[128], csum2[2][128];
  int b = blockIdx.x;
  int tid = threadIdx.x;

  if (b == 256) {  // ---- prep role (256 threads) ----
    int j = tid & 127, half = tid >> 7;
    if (tid < 128) {
      float mn = decf(minenc[tid]);
      float mx = decf(maxenc[tid]);
      mn_s[tid] = mn;
      s_s[tid] = 1.0f / ((mx > mn) ? (mx - mn) : 1.0f);
    }
    __syncthreads();
    float c = 0.f;
#pragma unroll
    for (int kb = 0; kb < 4; ++kb) {
      ushort_t w1buf[16], w2buf[16];
      int k0 = half * 64 + kb * 16;
#pragma unroll
      for (int kk = 0; kk < 16; ++kk) {
        int k = k0 + kk;
        float wp = s_s[k] * W1[k * 128 + j];
        ushort_t wb = f2bf(wp);
        w1buf[kk] = wb;
        c += mn_s[k] * bf2f(wb);  // fold against ROUNDED weight so it cancels
        w2buf[kk] = f2bf(W2[k * 128 + j]);
      }
      uint4* p1 = (uint4*)(Wt1 + j * 128 + k0);
      uint4* p2 = (uint4*)(Wt2 + j * 128 + k0);
      p1[0] = *(uint4*)&w1buf[0]; p1[1] = *(uint4*)&w1buf[8];
      p2[0] = *(uint4*)&w2buf[0]; p2[1] = *(uint4*)&w2buf[8];
    }
    csum2[half][j] = c;
    __syncthreads();
    if (tid < 128) {
      cvec[tid] = csum2[0][tid] + csum2[1][tid];
      czero[tid] = 0.f;
    }
    return;
  }

  // ---- build role (blocks 0..255) ----
  int nlo = b * width;
  int wcnt = N - nlo; if (wcnt > width) wcnt = width; if (wcnt < 0) wcnt = 0;

  for (int i = tid; i < WMAX; i += 256) cntS[i] = 0;

  int t0 = 0;
#pragma unroll
  for (int x = 0; x < 8; ++x) t0 += bcur[x * 256 + tid];
  scn[tid] = t0;
  __syncthreads();
  for (int off = 1; off < 256; off <<= 1) {
    int v = (tid >= off) ? scn[tid - off] : 0;
    __syncthreads();
    scn[tid] += v;
    __syncthreads();
  }
  if (tid == b) sbase = scn[b] - t0;
  __syncthreads();
  int base = sbase;

  int lens[8], offx[8], tot = 0;
#pragma unroll
  for (int x = 0; x < 8; ++x) {
    int l = bcur[x * 256 + b]; if (l > capx) l = capx;
    lens[x] = l; offx[x] = tot; tot += l;
  }
  bool fits = (tot <= BLDS);

  for (int x = 0; x < 8; ++x) {
    const unsigned* sp = staging + ((size_t)(x * 256 + b)) * capx;
    int len = lens[x], ox = offx[x];
    for (int i = tid; i < len; i += 256) {
      unsigned p = sp[i];
      if (fits) items[ox + i] = p;
      atomicAdd(&cntS[p >> srcbits], 1);
    }
  }
  __syncthreads();

  for (int i = tid; i < WMAX; i += 256)
    scn[i] = cntS[i] + ((i < wcnt) ? ovf_deg[nlo + i] : 0);
  __syncthreads();
  for (int off = 1; off < WMAX; off <<= 1) {
    int i0 = tid, i1 = tid + 256;
    int v0 = (i0 >= off) ? scn[i0 - off] : 0;
    int v1 = (i1 >= off) ? scn[i1 - off] : 0;
    __syncthreads();
    scn[i0] += v0; scn[i1] += v1;
    __syncthreads();
  }

  for (int i = tid; i < WMAX; i += 256) {
    int ov = (i < wcnt) ? ovf_deg[nlo + i] : 0;
    int orig = cntS[i] + ov;
    int ex = scn[i] - orig;
    lcur[i] = ex;
    if (i < wcnt) {
      rowptr[nlo + i] = base + ex;
      gcursor[nlo + i] = base + ex + cntS[i];
      dinv[nlo + i] = rsqrtf((float)orig + 1.0f);
    }
  }
  if (b == 255 && tid == 0) rowptr[N] = E;
  __syncthreads();

  if (fits) {
    for (int i = tid; i < tot; i += 256) {
      unsigned p = items[i];
      int pos = atomicAdd(&lcur[p >> srcbits], 1);
      adj[base + pos] = (int)(p & ((1u << srcbits) - 1u));
    }
  } else {
    for (int x = 0; x < 8; ++x) {
      const unsigned* sp = staging + ((size_t)(x * 256 + b)) * capx;
      int len = lens[x];
      for (int i = tid; i < len; i += 256) {
        unsigned p = sp[i];
        int pos = atomicAdd(&lcur[p >> srcbits], 1);
        adj[base + pos] = (int)(p & ((1u << srcbits) - 1u));
      }
    }
  }
  __syncthreads();

  int ovlen = ctrl[8]; if (ovlen > ovfcap) ovlen = ovfcap;
  if (ovlen > 0) {
    int nhi = nlo + wcnt;
    for (int i = tid; i < ovlen; i += 256) {
      int s = ovf[2 * i], d = ovf[2 * i + 1];
      if (d >= nlo && d < nhi) {
        int pos = atomicAdd(&gcursor[d], 1);
        adj[pos] = s;
      }
    }
  }
}

// ---- MFMA GEMM: g[bf16] = (X @ Wt^T - cvec) * dinv[row]  (r11) --------------
template <int XBF16>
__global__ __launch_bounds__(256) void gemm_mfma_kernel(
    const void* __restrict__ Xv, const ushort_t* __restrict__ Wtg,
    const float* __restrict__ cvec, const float* __restrict__ dinv,
    ushort_t* __restrict__ g, int N) {
  __shared__ ushort_t wt[128 * 128];  // XOR-swizzled
  int t = threadIdx.x;
  for (int c = t; c < 2048; c += 256) {
    int j = c >> 4;
    int ko = (c & 15) << 4;
    uint4 v = *(const uint4*)(Wtg + j * 128 + (ko >> 1));
    *(uint4*)((char*)wt + j * 256 + (ko ^ ((j & 7) << 4))) = v;
  }
  __syncthreads();

  int lane = t & 63, w = t >> 6;
  int lrow = lane & 15;
  int lk = lane >> 4;
  int rowA = blockIdx.x * 64 + w * 16 + lrow;
  int rA = (rowA < N) ? rowA : (N - 1);

  f32x4 acc[8];
#pragma unroll
  for (int i = 0; i < 8; ++i) acc[i] = (f32x4){0.f, 0.f, 0.f, 0.f};

#pragma unroll
  for (int ks = 0; ks < 4; ++ks) {
    int k0 = ks * 32;
    bf16x8 a;
    if (XBF16) {
      a = *(const bf16x8*)((const ushort_t*)Xv + (size_t)rA * 128 + k0 + lk * 8);
    } else {
      const float* xp = (const float*)Xv + (size_t)rA * 128 + k0 + lk * 8;
      float4 f0 = *(const float4*)xp;
      float4 f1 = *(const float4*)(xp + 4);
      bf16x8 tmp;
      tmp[0] = (short)f2bf(f0.x); tmp[1] = (short)f2bf(f0.y);
      tmp[2] = (short)f2bf(f0.z); tmp[3] = (short)f2bf(f0.w);
      tmp[4] = (short)f2bf(f1.x); tmp[5] = (short)f2bf(f1.y);
      tmp[6] = (short)f2bf(f1.z); tmp[7] = (short)f2bf(f1.w);
      a = tmp;
    }
    int koff = k0 * 2 + lk * 16;
#pragma unroll
    for (int tl = 0; tl < 8; ++tl) {
      int j = tl * 16 + lrow;
      bf16x8 bfr = *(const bf16x8*)((const char*)wt + j * 256 + (koff ^ ((j & 7) << 4)));
      acc[tl] = __builtin_amdgcn_mfma_f32_16x16x32_bf16(a, bfr, acc[tl], 0, 0, 0);
    }
  }

  int robase = blockIdx.x * 64 + w * 16 + (lane >> 4) * 4;
#pragma unroll
  for (int j = 0; j < 4; ++j) {
    int row = robase + j;
    if (row < N) {
      float dv = dinv[row];
#pragma unroll
      for (int tl = 0; tl < 8; ++tl) {
        int col = tl * 16 + lrow;
        float o = (acc[tl][j] - cvec[col]) * dv;
        g[(size_t)row * 128 + col] = f2bf(o);
      }
    }
  }
}

// ---- aggregate: 1 wave per dst; depth-4 batched row gathers (r11) -----------
template <int LAYER2>
__global__ __launch_bounds__(256) void aggregate_kernel(
    const int* __restrict__ rowptr, const int* __restrict__ adj,
    const ushort_t* __restrict__ g, const float* __restrict__ dinv,
    const float* __restrict__ b, void* __restrict__ out, int N) {
  int t = blockIdx.x * blockDim.x + threadIdx.x;
  int d = t >> 6;
  if (d >= N) return;
  int lane = t & 63;
  int sub = lane >> 4;
  int l = lane & 15;
  const ushort_t* gp = g + l * 8;

  float a0 = 0.f, a1 = 0.f, a2 = 0.f, a3 = 0.f,
        a4 = 0.f, a5 = 0.f, a6 = 0.f, a7 = 0.f;
  if (sub == 0) {  // self loop
    bf16x8 sv = *(const bf16x8*)(gp + (size_t)d * 128);
    a0 = bf2f(sv[0]); a1 = bf2f(sv[1]); a2 = bf2f(sv[2]); a3 = bf2f(sv[3]);
    a4 = bf2f(sv[4]); a5 = bf2f(sv[5]); a6 = bf2f(sv[6]); a7 = bf2f(sv[7]);
  }

  int beg = rowptr[d], end = rowptr[d + 1];
  int i = beg + sub;
  for (; i + 12 < end; i += 16) {
    int n0 = adj[i], n1 = adj[i + 4], n2 = adj[i + 8], n3 = adj[i + 12];
    bf16x8 v0 = *(const bf16x8*)(gp + (size_t)n0 * 128);
    bf16x8 v1 = *(const bf16x8*)(gp + (size_t)n1 * 128);
    bf16x8 v2 = *(const bf16x8*)(gp + (size_t)n2 * 128);
    bf16x8 v3 = *(const bf16x8*)(gp + (size_t)n3 * 128);
    a0 += (bf2f(v0[0]) + bf2f(v1[0])) + (bf2f(v2[0]) + bf2f(v3[0]));
    a1 += (bf2f(v0[1]) + bf2f(v1[1])) + (bf2f(v2[1]) + bf2f(v3[1]));
    a2 += (bf2f(v0[2]) + bf2f(v1[2])) + (bf2f(v2[2]) + bf2f(v3[2]));
    a3 += (bf2f(v0[3]) + bf2f(v1[3])) + (bf2f(v2[3]) + bf2f(v3[3]));
    a4 += (bf2f(v0[4]) + bf2f(v1[4])) + (bf2f(v2[4]) + bf2f(v3[4]));
    a5 += (bf2f(v0[5]) + bf2f(v1[5])) + (bf2f(v2[5]) + bf2f(v3[5]));
    a6 += (bf2f(v0[6]) + bf2f(v1[6])) + (bf2f(v2[6]) + bf2f(v3[6]));
    a7 += (bf2f(v0[7]) + bf2f(v1[7])) + (bf2f(v2[7]) + bf2f(v3[7]));
  }
  for (; i + 4 < end; i += 8) {
    int n0 = adj[i], n1 = adj[i + 4];
    bf16x8 v0 = *(const bf16x8*)(gp + (size_t)n0 * 128);
    bf16x8 v1 = *(const bf16x8*)(gp + (size_t)n1 * 128);
    a0 += bf2f(v0[0]) + bf2f(v1[0]); a1 += bf2f(v0[1]) + bf2f(v1[1]);
    a2 += bf2f(v0[2]) + bf2f(v1[2]); a3 += bf2f(v0[3]) + bf2f(v1[3]);
    a4 += bf2f(v0[4]) + bf2f(v1[4]); a5 += bf2f(v0[5]) + bf2f(v1[5]);
    a6 += bf2f(v0[6]) + bf2f(v1[6]); a7 += bf2f(v0[7]) + bf2f(v1[7]);
  }
  for (; i < end; i += 4) {
    int n = adj[i];
    bf16x8 v = *(const bf16x8*)(gp + (size_t)n * 128);
    a0 += bf2f(v[0]); a1 += bf2f(v[1]); a2 += bf2f(v[2]); a3 += bf2f(v[3]);
    a4 += bf2f(v[4]); a5 += bf2f(v[5]); a6 += bf2f(v[6]); a7 += bf2f(v[7]);
  }

  a0 += __shfl_xor(a0, 16); a1 += __shfl_xor(a1, 16);
  a2 += __shfl_xor(a2, 16); a3 += __shfl_xor(a3, 16);
  a4 += __shfl_xor(a4, 16); a5 += __shfl_xor(a5, 16);
  a6 += __shfl_xor(a6, 16); a7 += __shfl_xor(a7, 16);
  a0 += __shfl_xor(a0, 32); a1 += __shfl_xor(a1, 32);
  a2 += __shfl_xor(a2, 32); a3 += __shfl_xor(a3, 32);
  a4 += __shfl_xor(a4, 32); a5 += __shfl_xor(a5, 32);
  a6 += __shfl_xor(a6, 32); a7 += __shfl_xor(a7, 32);

  if (sub == 0) {
    float dv = dinv[d];
    const float4 bb0 = *(const float4*)&b[l * 8];
    const float4 bb1 = *(const float4*)&b[l * 8 + 4];
    float o0 = dv * a0 + bb0.x, o1 = dv * a1 + bb0.y;
    float o2 = dv * a2 + bb0.z, o3 = dv * a3 + bb0.w;
    float o4 = dv * a4 + bb1.x, o5 = dv * a5 + bb1.y;
    float o6 = dv * a6 + bb1.z, o7 = dv * a7 + bb1.w;
    if (!LAYER2) {  // relu + bf16 store (16B)
      o0 = fmaxf(o0, 0.f); o1 = fmaxf(o1, 0.f); o2 = fmaxf(o2, 0.f);
      o3 = fmaxf(o3, 0.f); o4 = fmaxf(o4, 0.f); o5 = fmaxf(o5, 0.f);
      o6 = fmaxf(o6, 0.f); o7 = fmaxf(o7, 0.f);
      bf16x8 ov;
      ov[0] = (short)f2bf(o0); ov[1] = (short)f2bf(o1);
      ov[2] = (short)f2bf(o2); ov[3] = (short)f2bf(o3);
      ov[4] = (short)f2bf(o4); ov[5] = (short)f2bf(o5);
      ov[6] = (short)f2bf(o6); ov[7] = (short)f2bf(o7);
      *(bf16x8*)((ushort_t*)out + (size_t)d * 128 + l * 8) = ov;
    } else {  // fp32 store (32B)
      float4 w0; w0.x = o0; w0.y = o1; w0.z = o2; w0.w = o3;
      float4 w1; w1.x = o4; w1.y = o5; w1.z = o6; w1.w = o7;
      float* op = (float*)out + (size_t)d * 128 + l * 8;
      *(float4*)op = w0;
      *(float4*)(op + 4) = w1;
    }
  }
}

extern "C" void kernel_launch(void* const* d_in, const int* in_sizes, int n_in,
                              void* d_out, int out_size, void* d_ws, size_t ws_size,
                              hipStream_t stream) {
  const float* features = (const float*)d_in[0];
  const float* W1 = (const float*)d_in[1];
  const float* b1 = (const float*)d_in[2];
  const float* W2 = (const float*)d_in[3];
  const float* b2 = (const float*)d_in[4];
  const void* edges = d_in[5];
  const int N = in_sizes[0] / 128;
  const int E = in_sizes[5] / 2;

  int srcbits = 1; while ((1LL << srcbits) < (long long)N) srcbits++;
  const int width = (N + 255) / 256;
  const unsigned M = (unsigned)(0x100000000ULL / (unsigned)width + 1);
  const int capx = (E / 2048) * 3 + 256;
  const int ovfcap = E / 4;

  float* ws = (float*)d_ws;
  size_t off = 0;
  ushort_t* gbuf = (ushort_t*)(ws + off);  off += (size_t)N * 64;  // bf16 N x 128
  ushort_t* h1 = (ushort_t*)(ws + off);    off += (size_t)N * 64;  // bf16 N x 128
  int* rowptr = (int*)(ws + off);      off += N + 4;
  int* gcursor = (int*)(ws + off);     off += N + 4;
  int* adj = (int*)(ws + off);         off += E;
  int* ovf_deg = (int*)(ws + off);     off += N + 4;
  float* dinv = ws + off;              off += N + 4;
  unsigned* minenc = (unsigned*)(ws + off); off += 128;
  unsigned* maxenc = (unsigned*)(ws + off); off += 128;
  ushort_t* Wt1 = (ushort_t*)(ws + off);    off += 128 * 64;
  ushort_t* Wt2 = (ushort_t*)(ws + off);    off += 128 * 64;
  float* cvec = ws + off;              off += 128;
  float* czero = ws + off;             off += 128;
  int* flag64 = (int*)(ws + off);      off += 4;
  int* ctrl = (int*)(ws + off);        off += 32;
  int* bcur = (int*)(ws + off);        off += 2048;
  unsigned* staging = (unsigned*)(ws + off); off += (size_t)2048 * capx;
  int* ovf = (int*)(ws + off);         off += 2 * (size_t)ovfcap;

  float* outf = (float*)d_out;

  // ---- prep chain (7 launches total) ----
  init_kernel<<<(N + 255) / 256, 256, 0, stream>>>(
      (const int*)edges, E, flag64, minenc, maxenc, ovf_deg, bcur, ctrl, N);
  partition_kernel<<<CMB + 1024, 256, 0, stream>>>(
      features, minenc, maxenc, edges, E, flag64, staging, capx,
      ovf, ovfcap, ovf_deg, bcur, ctrl, srcbits, M, width, N);
  build_kernel<<<257, 256, 0, stream>>>(
      staging, capx, bcur, ovf_deg, ovf, ovfcap, ctrl,
      rowptr, gcursor, dinv, adj,
      minenc, maxenc, W1, W2, Wt1, Wt2, cvec, czero,
      N, E, srcbits, width);

  // ---- layer 1 ----
  gemm_mfma_kernel<0><<<(N + 63) / 64, 256, 0, stream>>>(
      features, Wt1, cvec, dinv, gbuf, N);
  aggregate_kernel<0><<<((size_t)N * 64 + 255) / 256, 256, 0, stream>>>(
      rowptr, adj, gbuf, dinv, b1, h1, N);

  // ---- layer 2 ----
  gemm_mfma_kernel<1><<<(N + 63) / 64, 256, 0, stream>>>(
      h1, Wt2, czero, dinv, gbuf, N);
  aggregate_kernel<1><<<((size_t)N * 64 + 255) / 256, 256, 0, stream>>>(
      rowptr, adj, gbuf, dinv, b2, outf, N);
}

// Round 15
// 277.968 us; speedup vs baseline: 2.5214x; 1.1619x over previous
//
#include <hip/hip_runtime.h>

// ---------------------------------------------------------------------------
// MORAL 2-layer GCN on MI355X — round 15.
//   = r11 (best measured, 278.6us) reverted verbatim, with ONE change:
//   partition PCHUNK 2048->4096 (PITER 16). Halves the per-chunk overhead
//   rounds (LDS hist zero+scan, 256 returning bcur atomics, 2 barriers per
//   round) and doubles per-thread nt-loads in flight. r14's fusions reverted
//   (queue-line ping-pong + role co-scheduling caused the 137us partition).
// ---------------------------------------------------------------------------

typedef short bf16x8 __attribute__((ext_vector_type(8)));
typedef float f32x4 __attribute__((ext_vector_type(4)));
typedef unsigned short ushort_t;

__device__ __forceinline__ unsigned encf(float f) {
  unsigned u = __float_as_uint(f);
  return (u & 0x80000000u) ? ~u : (u | 0x80000000u);
}
__device__ __forceinline__ float decf(unsigned e) {
  unsigned u = (e & 0x80000000u) ? (e ^ 0x80000000u) : ~e;
  return __uint_as_float(u);
}
__device__ __forceinline__ ushort_t f2bf(float f) {
  unsigned u = __float_as_uint(f);
  u += 0x7FFF + ((u >> 16) & 1);  // RNE
  return (ushort_t)(u >> 16);
}
__device__ __forceinline__ float bf2f(ushort_t h) {
  return __uint_as_float((unsigned)h << 16);
}

// ---- init + edge-dtype detect ----------------------------------------------
__global__ void init_kernel(const int* __restrict__ edges, int E, int* flag64,
                            unsigned* minenc, unsigned* maxenc, int* ovf_deg,
                            int* bcur, int* ctrl, int N) {
  int i = blockIdx.x * blockDim.x + threadIdx.x;
  if (i < 128) { minenc[i] = 0xFFFFFFFFu; maxenc[i] = 0u; }
  if (i < 2048) bcur[i] = 0;
  if (i < 32) ctrl[i] = 0;
  if (i < N) ovf_deg[i] = 0;
  if (blockIdx.x == 0) {
    __shared__ int any_nz;
    if (threadIdx.x == 0) any_nz = 0;
    __syncthreads();
    int idx = 2 * (int)threadIdx.x + 1;
    if (threadIdx.x < 128 && idx < 2 * E && edges[idx] != 0) any_nz = 1;
    __syncthreads();
    if (threadIdx.x == 0) *flag64 = !any_nz;
  }
}

__global__ void colminmax_kernel(const float* __restrict__ x, unsigned* minenc,
                                 unsigned* maxenc, int N) {
  int g = blockIdx.x * blockDim.x + threadIdx.x;
  int col = g & 127;
  int r0 = g >> 7;
  int nstream = (gridDim.x * blockDim.x) >> 7;
  float mn = 3.4e38f, mx = -3.4e38f;
  for (int r = r0; r < N; r += nstream) {
    float v = x[(size_t)r * 128 + col];
    mn = fminf(mn, v); mx = fmaxf(mx, v);
  }
  atomicMin(&minenc[col], encf(mn));
  atomicMax(&maxenc[col], encf(mx));
}

// Wt1[j][k] = bf16(s[k]*W1[k][j]); cvec[j] = sum_k mn[k]*float(Wt1[j][k])
__global__ __launch_bounds__(1024) void prep_kernel(
    const unsigned* __restrict__ minenc, const unsigned* __restrict__ maxenc,
    const float* __restrict__ W1, const float* __restrict__ W2,
    ushort_t* __restrict__ Wt1, ushort_t* __restrict__ Wt2,
    float* __restrict__ cvec, float* __restrict__ czero) {
  __shared__ float mn_s[128], s_s[128];
  __shared__ float csum[8][128];
  int tid = threadIdx.x;
  int j = tid & 127, kg = tid >> 7;
  if (tid < 128) {
    float mn = decf(minenc[tid]);
    float mx = decf(maxenc[tid]);
    mn_s[tid] = mn;
    s_s[tid] = 1.0f / ((mx > mn) ? (mx - mn) : 1.0f);
  }
  __syncthreads();
  ushort_t w1buf[16], w2buf[16];
  float c = 0.f;
#pragma unroll
  for (int kk = 0; kk < 16; ++kk) {
    int k = kg * 16 + kk;
    float wp = s_s[k] * W1[k * 128 + j];
    ushort_t wb = f2bf(wp);
    w1buf[kk] = wb;
    c += mn_s[k] * bf2f(wb);  // fold against ROUNDED weight so it cancels
    w2buf[kk] = f2bf(W2[k * 128 + j]);
  }
  {
    uint4* p1 = (uint4*)(Wt1 + j * 128 + kg * 16);
    uint4* p2 = (uint4*)(Wt2 + j * 128 + kg * 16);
    p1[0] = *(uint4*)&w1buf[0]; p1[1] = *(uint4*)&w1buf[8];
    p2[0] = *(uint4*)&w2buf[0]; p2[1] = *(uint4*)&w2buf[8];
  }
  csum[kg][j] = c;
  __syncthreads();
  if (tid < 128) {
    float t = 0.f;
#pragma unroll
    for (int x = 0; x < 8; ++x) t += csum[x][tid];
    cvec[tid] = t;
    czero[tid] = 0.f;
  }
}

// ---- Phase 1: MSB-radix partition (r11 structure, bigger chunks) ------------
#define PITER 16
#define PCHUNK 4096

__global__ __launch_bounds__(256) void partition_kernel(
    const void* __restrict__ edges, int E, const int* __restrict__ flag64,
    unsigned* __restrict__ staging, int capx,
    int* __restrict__ ovf, int ovfcap, int* __restrict__ ovf_deg,
    int* __restrict__ bcur, int* __restrict__ ctrl,
    int srcbits, unsigned M, int width) {
  __shared__ unsigned pk_s[PCHUNK];
  __shared__ unsigned char bk_s[PCHUNK];
  __shared__ int hist[256], rbase[256], lcur[256];
  __shared__ int chunk_s;
  int xcd;
  asm volatile("s_getreg_b32 %0, hwreg(HW_REG_XCC_ID)" : "=s"(xcd));
  xcd &= 7;
  const int elo = (int)(((long long)E * xcd) >> 3);
  const int ehi = (int)(((long long)E * (xcd + 1)) >> 3);
  const int is64 = *flag64;
  const int tid = threadIdx.x;

  for (;;) {
    __syncthreads();
    if (tid == 0) chunk_s = atomicAdd(&ctrl[xcd], 1);
    hist[tid] = 0;
    __syncthreads();
    int base = elo + chunk_s * PCHUNK;
    if (base >= ehi) break;
    int cnt = ehi - base; if (cnt > PCHUNK) cnt = PCHUNK;
#pragma unroll
    for (int i = 0; i < PITER; ++i) {
      int idx = i * 256 + tid;
      if (idx < cnt) {
        int e = base + idx;
        int s, d;
        if (is64) {
          s = (int)__builtin_nontemporal_load((const long long*)edges + e);
          d = (int)__builtin_nontemporal_load((const long long*)edges + E + e);
        } else {
          s = __builtin_nontemporal_load((const int*)edges + e);
          d = __builtin_nontemporal_load((const int*)edges + E + e);
        }
        unsigned b = __umulhi((unsigned)d, M);  // b = d / width (exact)
        int dloc = d - (int)b * width;
        pk_s[idx] = ((unsigned)dloc << srcbits) | (unsigned)s;
        bk_s[idx] = (unsigned char)b;
        atomicAdd(&hist[b], 1);
      }
    }
    __syncthreads();
    {
      int h = hist[tid];
      rbase[tid] = h ? atomicAdd(&bcur[xcd * 256 + tid], h) : 0;
      lcur[tid] = 0;
    }
    __syncthreads();
#pragma unroll
    for (int i = 0; i < PITER; ++i) {
      int idx = i * 256 + tid;
      if (idx < cnt) {
        int b = bk_s[idx];
        unsigned p = pk_s[idx];
        int j = atomicAdd(&lcur[b], 1);
        int pos = rbase[b] + j;
        if (pos < capx) {
          staging[((size_t)(xcd * 256 + b)) * capx + pos] = p;
        } else {  // overflow (statistically never for uniform dst)
          int op = atomicAdd(&ctrl[8], 1);
          if (op < ovfcap) {
            int s = (int)(p & ((1u << srcbits) - 1u));
            int d = b * width + (int)(p >> srcbits);
            ovf[2 * op] = s; ovf[2 * op + 1] = d;
            atomicAdd(&ovf_deg[d], 1);
          }
        }
      }
    }
  }
}

// ---- Phase 2: per-bucket build (r11) -----------------------------------------
#define WMAX 512
#define BLDS 12288

__global__ __launch_bounds__(256) void build_kernel(
    const unsigned* __restrict__ staging, int capx,
    const int* __restrict__ bcur, const int* __restrict__ ovf_deg,
    const int* __restrict__ ovf, int ovfcap, const int* __restrict__ ctrl,
    int* __restrict__ rowptr, int* __restrict__ gcursor,
    float* __restrict__ dinv, int* __restrict__ adj,
    int N, int E, int srcbits, int width) {
  __shared__ int cntS[WMAX], scn[WMAX], lcur[WMAX];
  __shared__ unsigned items[BLDS];
  __shared__ int sbase;
  int b = blockIdx.x;
  int tid = threadIdx.x;
  int nlo = b * width;
  int wcnt = N - nlo; if (wcnt > width) wcnt = width; if (wcnt < 0) wcnt = 0;

  for (int i = tid; i < WMAX; i += 256) cntS[i] = 0;

  int t0 = 0;
#pragma unroll
  for (int x = 0; x < 8; ++x) t0 += bcur[x * 256 + tid];
  scn[tid] = t0;
  __syncthreads();
  for (int off = 1; off < 256; off <<= 1) {
    int v = (tid >= off) ? scn[tid - off] : 0;
    __syncthreads();
    scn[tid] += v;
    __syncthreads();
  }
  if (tid == b) sbase = scn[b] - t0;
  __syncthreads();
  int base = sbase;

  int lens[8], offx[8], tot = 0;
#pragma unroll
  for (int x = 0; x < 8; ++x) {
    int l = bcur[x * 256 + b]; if (l > capx) l = capx;
    lens[x] = l; offx[x] = tot; tot += l;
  }
  bool fits = (tot <= BLDS);

  for (int x = 0; x < 8; ++x) {
    const unsigned* sp = staging + ((size_t)(x * 256 + b)) * capx;
    int len = lens[x], ox = offx[x];
    for (int i = tid; i < len; i += 256) {
      unsigned p = sp[i];
      if (fits) items[ox + i] = p;
      atomicAdd(&cntS[p >> srcbits], 1);
    }
  }
  __syncthreads();

  for (int i = tid; i < WMAX; i += 256)
    scn[i] = cntS[i] + ((i < wcnt) ? ovf_deg[nlo + i] : 0);
  __syncthreads();
  for (int off = 1; off < WMAX; off <<= 1) {
    int i0 = tid, i1 = tid + 256;
    int v0 = (i0 >= off) ? scn[i0 - off] : 0;
    int v1 = (i1 >= off) ? scn[i1 - off] : 0;
    __syncthreads();
    scn[i0] += v0; scn[i1] += v1;
    __syncthreads();
  }

  for (int i = tid; i < WMAX; i += 256) {
    int ov = (i < wcnt) ? ovf_deg[nlo + i] : 0;
    int orig = cntS[i] + ov;
    int ex = scn[i] - orig;
    lcur[i] = ex;
    if (i < wcnt) {
      rowptr[nlo + i] = base + ex;
      gcursor[nlo + i] = base + ex + cntS[i];
      dinv[nlo + i] = rsqrtf((float)orig + 1.0f);
    }
  }
  if (b == gridDim.x - 1 && tid == 0) rowptr[N] = E;
  __syncthreads();

  if (fits) {
    for (int i = tid; i < tot; i += 256) {
      unsigned p = items[i];
      int pos = atomicAdd(&lcur[p >> srcbits], 1);
      adj[base + pos] = (int)(p & ((1u << srcbits) - 1u));
    }
  } else {
    for (int x = 0; x < 8; ++x) {
      const unsigned* sp = staging + ((size_t)(x * 256 + b)) * capx;
      int len = lens[x];
      for (int i = tid; i < len; i += 256) {
        unsigned p = sp[i];
        int pos = atomicAdd(&lcur[p >> srcbits], 1);
        adj[base + pos] = (int)(p & ((1u << srcbits) - 1u));
      }
    }
  }
  __syncthreads();

  int ovlen = ctrl[8]; if (ovlen > ovfcap) ovlen = ovfcap;
  if (ovlen > 0) {
    int nhi = nlo + wcnt;
    for (int i = tid; i < ovlen; i += 256) {
      int s = ovf[2 * i], d = ovf[2 * i + 1];
      if (d >= nlo && d < nhi) {
        int pos = atomicAdd(&gcursor[d], 1);
        adj[pos] = s;
      }
    }
  }
}

// ---- MFMA GEMM: g[bf16] = (X @ Wt^T - cvec) * dinv[row]  (r11) --------------
template <int XBF16>
__global__ __launch_bounds__(256) void gemm_mfma_kernel(
    const void* __restrict__ Xv, const ushort_t* __restrict__ Wtg,
    const float* __restrict__ cvec, const float* __restrict__ dinv,
    ushort_t* __restrict__ g, int N) {
  __shared__ ushort_t wt[128 * 128];  // XOR-swizzled
  int t = threadIdx.x;
  for (int c = t; c < 2048; c += 256) {
    int j = c >> 4;
    int ko = (c & 15) << 4;
    uint4 v = *(const uint4*)(Wtg + j * 128 + (ko >> 1));
    *(uint4*)((char*)wt + j * 256 + (ko ^ ((j & 7) << 4))) = v;
  }
  __syncthreads();

  int lane = t & 63, w = t >> 6;
  int lrow = lane & 15;
  int lk = lane >> 4;
  int rowA = blockIdx.x * 64 + w * 16 + lrow;
  int rA = (rowA < N) ? rowA : (N - 1);

  f32x4 acc[8];
#pragma unroll
  for (int i = 0; i < 8; ++i) acc[i] = (f32x4){0.f, 0.f, 0.f, 0.f};

#pragma unroll
  for (int ks = 0; ks < 4; ++ks) {
    int k0 = ks * 32;
    bf16x8 a;
    if (XBF16) {
      a = *(const bf16x8*)((const ushort_t*)Xv + (size_t)rA * 128 + k0 + lk * 8);
    } else {
      const float* xp = (const float*)Xv + (size_t)rA * 128 + k0 + lk * 8;
      float4 f0 = *(const float4*)xp;
      float4 f1 = *(const float4*)(xp + 4);
      bf16x8 tmp;
      tmp[0] = (short)f2bf(f0.x); tmp[1] = (short)f2bf(f0.y);
      tmp[2] = (short)f2bf(f0.z); tmp[3] = (short)f2bf(f0.w);
      tmp[4] = (short)f2bf(f1.x); tmp[5] = (short)f2bf(f1.y);
      tmp[6] = (short)f2bf(f1.z); tmp[7] = (short)f2bf(f1.w);
      a = tmp;
    }
    int koff = k0 * 2 + lk * 16;
#pragma unroll
    for (int tl = 0; tl < 8; ++tl) {
      int j = tl * 16 + lrow;
      bf16x8 bfr = *(const bf16x8*)((const char*)wt + j * 256 + (koff ^ ((j & 7) << 4)));
      acc[tl] = __builtin_amdgcn_mfma_f32_16x16x32_bf16(a, bfr, acc[tl], 0, 0, 0);
    }
  }

  int robase = blockIdx.x * 64 + w * 16 + (lane >> 4) * 4;
#pragma unroll
  for (int j = 0; j < 4; ++j) {
    int row = robase + j;
    if (row < N) {
      float dv = dinv[row];
#pragma unroll
      for (int tl = 0; tl < 8; ++tl) {
        int col = tl * 16 + lrow;
        float o = (acc[tl][j] - cvec[col]) * dv;
        g[(size_t)row * 128 + col] = f2bf(o);
      }
    }
  }
}

// ---- aggregate: 1 wave per dst; depth-4 batched row gathers (r11) -----------
template <int LAYER2>
__global__ __launch_bounds__(256) void aggregate_kernel(
    const int* __restrict__ rowptr, const int* __restrict__ adj,
    const ushort_t* __restrict__ g, const float* __restrict__ dinv,
    const float* __restrict__ b, void* __restrict__ out, int N) {
  int t = blockIdx.x * blockDim.x + threadIdx.x;
  int d = t >> 6;
  if (d >= N) return;
  int lane = t & 63;
  int sub = lane >> 4;
  int l = lane & 15;
  const ushort_t* gp = g + l * 8;

  float a0 = 0.f, a1 = 0.f, a2 = 0.f, a3 = 0.f,
        a4 = 0.f, a5 = 0.f, a6 = 0.f, a7 = 0.f;
  if (sub == 0) {  // self loop
    bf16x8 sv = *(const bf16x8*)(gp + (size_t)d * 128);
    a0 = bf2f(sv[0]); a1 = bf2f(sv[1]); a2 = bf2f(sv[2]); a3 = bf2f(sv[3]);
    a4 = bf2f(sv[4]); a5 = bf2f(sv[5]); a6 = bf2f(sv[6]); a7 = bf2f(sv[7]);
  }

  int beg = rowptr[d], end = rowptr[d + 1];
  int i = beg + sub;
  for (; i + 12 < end; i += 16) {
    int n0 = adj[i], n1 = adj[i + 4], n2 = adj[i + 8], n3 = adj[i + 12];
    bf16x8 v0 = *(const bf16x8*)(gp + (size_t)n0 * 128);
    bf16x8 v1 = *(const bf16x8*)(gp + (size_t)n1 * 128);
    bf16x8 v2 = *(const bf16x8*)(gp + (size_t)n2 * 128);
    bf16x8 v3 = *(const bf16x8*)(gp + (size_t)n3 * 128);
    a0 += (bf2f(v0[0]) + bf2f(v1[0])) + (bf2f(v2[0]) + bf2f(v3[0]));
    a1 += (bf2f(v0[1]) + bf2f(v1[1])) + (bf2f(v2[1]) + bf2f(v3[1]));
    a2 += (bf2f(v0[2]) + bf2f(v1[2])) + (bf2f(v2[2]) + bf2f(v3[2]));
    a3 += (bf2f(v0[3]) + bf2f(v1[3])) + (bf2f(v2[3]) + bf2f(v3[3]));
    a4 += (bf2f(v0[4]) + bf2f(v1[4])) + (bf2f(v2[4]) + bf2f(v3[4]));
    a5 += (bf2f(v0[5]) + bf2f(v1[5])) + (bf2f(v2[5]) + bf2f(v3[5]));
    a6 += (bf2f(v0[6]) + bf2f(v1[6])) + (bf2f(v2[6]) + bf2f(v3[6]));
    a7 += (bf2f(v0[7]) + bf2f(v1[7])) + (bf2f(v2[7]) + bf2f(v3[7]));
  }
  for (; i + 4 < end; i += 8) {
    int n0 = adj[i], n1 = adj[i + 4];
    bf16x8 v0 = *(const bf16x8*)(gp + (size_t)n0 * 128);
    bf16x8 v1 = *(const bf16x8*)(gp + (size_t)n1 * 128);
    a0 += bf2f(v0[0]) + bf2f(v1[0]); a1 += bf2f(v0[1]) + bf2f(v1[1]);
    a2 += bf2f(v0[2]) + bf2f(v1[2]); a3 += bf2f(v0[3]) + bf2f(v1[3]);
    a4 += bf2f(v0[4]) + bf2f(v1[4]); a5 += bf2f(v0[5]) + bf2f(v1[5]);
    a6 += bf2f(v0[6]) + bf2f(v1[6]); a7 += bf2f(v0[7]) + bf2f(v1[7]);
  }
  for (; i < end; i += 4) {
    int n = adj[i];
    bf16x8 v = *(const bf16x8*)(gp + (size_t)n * 128);
    a0 += bf2f(v[0]); a1 += bf2f(v[1]); a2 += bf2f(v[2]); a3 += bf2f(v[3]);
    a4 += bf2f(v[4]); a5 += bf2f(v[5]); a6 += bf2f(v[6]); a7 += bf2f(v[7]);
  }

  a0 += __shfl_xor(a0, 16); a1 += __shfl_xor(a1, 16);
  a2 += __shfl_xor(a2, 16); a3 += __shfl_xor(a3, 16);
  a4 += __shfl_xor(a4, 16); a5 += __shfl_xor(a5, 16);
  a6 += __shfl_xor(a6, 16); a7 += __shfl_xor(a7, 16);
  a0 += __shfl_xor(a0, 32); a1 += __shfl_xor(a1, 32);
  a2 += __shfl_xor(a2, 32); a3 += __shfl_xor(a3, 32);
  a4 += __shfl_xor(a4, 32); a5 += __shfl_xor(a5, 32);
  a6 += __shfl_xor(a6, 32); a7 += __shfl_xor(a7, 32);

  if (sub == 0) {
    float dv = dinv[d];
    const float4 bb0 = *(const float4*)&b[l * 8];
    const float4 bb1 = *(const float4*)&b[l * 8 + 4];
    float o0 = dv * a0 + bb0.x, o1 = dv * a1 + bb0.y;
    float o2 = dv * a2 + bb0.z, o3 = dv * a3 + bb0.w;
    float o4 = dv * a4 + bb1.x, o5 = dv * a5 + bb1.y;
    float o6 = dv * a6 + bb1.z, o7 = dv * a7 + bb1.w;
    if (!LAYER2) {  // relu + bf16 store (16B)
      o0 = fmaxf(o0, 0.f); o1 = fmaxf(o1, 0.f); o2 = fmaxf(o2, 0.f);
      o3 = fmaxf(o3, 0.f); o4 = fmaxf(o4, 0.f); o5 = fmaxf(o5, 0.f);
      o6 = fmaxf(o6, 0.f); o7 = fmaxf(o7, 0.f);
      bf16x8 ov;
      ov[0] = (short)f2bf(o0); ov[1] = (short)f2bf(o1);
      ov[2] = (short)f2bf(o2); ov[3] = (short)f2bf(o3);
      ov[4] = (short)f2bf(o4); ov[5] = (short)f2bf(o5);
      ov[6] = (short)f2bf(o6); ov[7] = (short)f2bf(o7);
      *(bf16x8*)((ushort_t*)out + (size_t)d * 128 + l * 8) = ov;
    } else {  // fp32 store (32B)
      float4 w0; w0.x = o0; w0.y = o1; w0.z = o2; w0.w = o3;
      float4 w1; w1.x = o4; w1.y = o5; w1.z = o6; w1.w = o7;
      float* op = (float*)out + (size_t)d * 128 + l * 8;
      *(float4*)op = w0;
      *(float4*)(op + 4) = w1;
    }
  }
}

extern "C" void kernel_launch(void* const* d_in, const int* in_sizes, int n_in,
                              void* d_out, int out_size, void* d_ws, size_t ws_size,
                              hipStream_t stream) {
  const float* features = (const float*)d_in[0];
  const float* W1 = (const float*)d_in[1];
  const float* b1 = (const float*)d_in[2];
  const float* W2 = (const float*)d_in[3];
  const float* b2 = (const float*)d_in[4];
  const void* edges = d_in[5];
  const int N = in_sizes[0] / 128;
  const int E = in_sizes[5] / 2;

  int srcbits = 1; while ((1LL << srcbits) < (long long)N) srcbits++;
  const int width = (N + 255) / 256;
  const unsigned M = (unsigned)(0x100000000ULL / (unsigned)width + 1);
  const int capx = (E / 2048) * 3 + 256;
  const int ovfcap = E / 4;

  float* ws = (float*)d_ws;
  size_t off = 0;
  ushort_t* gbuf = (ushort_t*)(ws + off);  off += (size_t)N * 64;  // bf16 N x 128
  ushort_t* h1 = (ushort_t*)(ws + off);    off += (size_t)N * 64;  // bf16 N x 128
  int* rowptr = (int*)(ws + off);      off += N + 4;
  int* gcursor = (int*)(ws + off);     off += N + 4;
  int* adj = (int*)(ws + off);         off += E;
  int* ovf_deg = (int*)(ws + off);     off += N + 4;
  float* dinv = ws + off;              off += N + 4;
  unsigned* minenc = (unsigned*)(ws + off); off += 128;
  unsigned* maxenc = (unsigned*)(ws + off); off += 128;
  ushort_t* Wt1 = (ushort_t*)(ws + off);    off += 128 * 64;
  ushort_t* Wt2 = (ushort_t*)(ws + off);    off += 128 * 64;
  float* cvec = ws + off;              off += 128;
  float* czero = ws + off;             off += 128;
  int* flag64 = (int*)(ws + off);      off += 4;
  int* ctrl = (int*)(ws + off);        off += 32;
  int* bcur = (int*)(ws + off);        off += 2048;
  unsigned* staging = (unsigned*)(ws + off); off += (size_t)2048 * capx;
  int* ovf = (int*)(ws + off);         off += 2 * (size_t)ovfcap;

  float* outf = (float*)d_out;

  // ---- graph + weight prep ----
  init_kernel<<<(N + 255) / 256, 256, 0, stream>>>(
      (const int*)edges, E, flag64, minenc, maxenc, ovf_deg, bcur, ctrl, N);
  colminmax_kernel<<<512, 256, 0, stream>>>(features, minenc, maxenc, N);
  prep_kernel<<<1, 1024, 0, stream>>>(minenc, maxenc, W1, W2, Wt1, Wt2, cvec, czero);
  partition_kernel<<<1024, 256, 0, stream>>>(edges, E, flag64, staging, capx,
                                             ovf, ovfcap, ovf_deg, bcur, ctrl,
                                             srcbits, M, width);
  build_kernel<<<256, 256, 0, stream>>>(staging, capx, bcur, ovf_deg,
                                        ovf, ovfcap, ctrl,
                                        rowptr, gcursor, dinv, adj,
                                        N, E, srcbits, width);

  // ---- layer 1 ----
  gemm_mfma_kernel<0><<<(N + 63) / 64, 256, 0, stream>>>(
      features, Wt1, cvec, dinv, gbuf, N);
  aggregate_kernel<0><<<((size_t)N * 64 + 255) / 256, 256, 0, stream>>>(
      rowptr, adj, gbuf, dinv, b1, h1, N);

  // ---- layer 2 ----
  gemm_mfma_kernel<1><<<(N + 63) / 64, 256, 0, stream>>>(
      h1, Wt2, czero, dinv, gbuf, N);
  aggregate_kernel<1><<<((size_t)N * 64 + 255) / 256, 256, 0, stream>>>(
      rowptr, adj, gbuf, dinv, b2, outf, N);
}